// Round 1
// baseline (993.069 us; speedup 1.0000x reference)
//
#include <hip/hip_runtime.h>
#include <stdint.h>

#define BATCH 16
#define NVOX (128*128*128)      // 2,097,152 per batch
#define KSEL 16384
#define HBINS 65536
#define BINCAP 16384
#define EQCAP 8192

// ctrl per batch: 16 u32: [0]=candCnt [1]=binCnt [2]=eqCnt [3]=P16 [4]=Cgt16

__global__ __launch_bounds__(256) void k_hist(const float* __restrict__ vox,
                                              uint32_t* __restrict__ hist1) {
  const int b = blockIdx.y;
  __shared__ uint32_t lh[768];              // bins 0x3D00..0x3FFF (v >= 2^-5)
  for (int i = threadIdx.x; i < 768; i += 256) lh[i] = 0;
  __syncthreads();
  const float4* v4 = (const float4*)(vox + (size_t)b * NVOX);
  uint32_t* h = hist1 + (size_t)b * HBINS;
  const int n4 = NVOX / 4;
  for (int i = blockIdx.x * 256 + threadIdx.x; i < n4; i += gridDim.x * 256) {
    float4 v = v4[i];
    float f[4] = {v.x, v.y, v.z, v.w};
#pragma unroll
    for (int c = 0; c < 4; ++c) {
      if (f[c] > 0.0f) {
        uint32_t p16 = __float_as_uint(f[c]) >> 16;
        uint32_t w = p16 - 0x3D00u;
        if (w < 768u) atomicAdd(&lh[w], 1u);
        else          atomicAdd(&h[p16], 1u);
      }
    }
  }
  __syncthreads();
  for (int i = threadIdx.x; i < 768; i += 256)
    if (lh[i]) atomicAdd(&h[0x3D00u + i], lh[i]);
}

__global__ __launch_bounds__(1024) void k_scan1(const uint32_t* __restrict__ hist1,
                                                uint32_t* __restrict__ ctrl) {
  const int b = blockIdx.x;
  const uint32_t* h = hist1 + (size_t)b * HBINS;
  __shared__ uint32_t part[1024];
  uint32_t s = 0;
  const int base = threadIdx.x * 64;
  for (int i = 0; i < 64; ++i) s += h[base + i];
  part[threadIdx.x] = s;
  __syncthreads();
  if (threadIdx.x == 0) {
    uint32_t acc = 0;
    for (int c = 1023; c >= 0; --c) {
      if (acc + part[c] >= (uint32_t)KSEL) {
        uint32_t run = acc;
        for (int bin = c * 64 + 63;; --bin) {
          uint32_t hv = h[bin];
          if (run + hv >= (uint32_t)KSEL) {
            ctrl[b * 16 + 3] = (uint32_t)bin;   // P16
            ctrl[b * 16 + 4] = run;             // Cgt16 = S(P16+1)
            break;
          }
          run += hv;
        }
        break;
      }
      acc += part[c];
    }
  }
}

__global__ __launch_bounds__(256) void k_gather(const float* __restrict__ vox,
                                                uint32_t* __restrict__ ctrl,
                                                unsigned long long* __restrict__ cand,
                                                unsigned long long* __restrict__ binlist,
                                                uint32_t* __restrict__ hist2) {
  const int b = blockIdx.y;
  const uint32_t P16 = ctrl[b * 16 + 3];
  const float4* v4 = (const float4*)(vox + (size_t)b * NVOX);
  uint32_t* h2 = hist2 + (size_t)b * HBINS;
  const int n4 = NVOX / 4;
  for (int i = blockIdx.x * 256 + threadIdx.x; i < n4; i += gridDim.x * 256) {
    float4 v = v4[i];
    float f[4] = {v.x, v.y, v.z, v.w};
#pragma unroll
    for (int c = 0; c < 4; ++c) {
      if (f[c] > 0.0f) {
        uint32_t bits = __float_as_uint(f[c]);
        uint32_t p16 = bits >> 16;
        if (p16 < P16) continue;
        uint32_t idx = (uint32_t)(i * 4 + c);
        unsigned long long key =
            ((unsigned long long)bits << 32) | (unsigned long long)(0xFFFFFFFFu - idx);
        if (p16 > P16) {
          uint32_t pos = atomicAdd(&ctrl[b * 16 + 0], 1u);
          cand[(size_t)b * KSEL + pos] = key;       // pos < KSEL guaranteed
        } else {
          uint32_t pos = atomicAdd(&ctrl[b * 16 + 1], 1u);
          if (pos < (uint32_t)BINCAP) binlist[(size_t)b * BINCAP + pos] = key;
          atomicAdd(&h2[bits & 0xFFFFu], 1u);
        }
      }
    }
  }
}

__global__ __launch_bounds__(1024) void k_finalize(const uint32_t* __restrict__ hist2,
                                                   uint32_t* __restrict__ ctrl,
                                                   unsigned long long* __restrict__ cand,
                                                   const unsigned long long* __restrict__ binlist,
                                                   uint32_t* __restrict__ eqbuf) {
  const int b = blockIdx.x;
  uint32_t* ct = ctrl + b * 16;
  const uint32_t Cgt16 = ct[4];
  const uint32_t P16 = ct[3];
  const uint32_t rem = (uint32_t)KSEL - Cgt16;     // >= 1
  const uint32_t* h2 = hist2 + (size_t)b * HBINS;
  __shared__ uint32_t part[1024];
  __shared__ uint32_t sL, sT, sEq;
  __shared__ uint32_t eqs[EQCAP];
  uint32_t s = 0;
  const int base = threadIdx.x * 64;
  for (int i = 0; i < 64; ++i) s += h2[base + i];
  part[threadIdx.x] = s;
  __syncthreads();
  if (threadIdx.x == 0) {
    uint32_t acc = 0;
    for (int c = 1023; c >= 0; --c) {
      if (acc + part[c] >= rem) {
        uint32_t run = acc;
        for (int bin = c * 64 + 63;; --bin) {
          uint32_t hv = h2[bin];
          if (run + hv >= rem) { sL = (uint32_t)bin; sT = rem - run; break; }
          run += hv;
        }
        break;
      }
      acc += part[c];
    }
  }
  __syncthreads();
  const uint32_t L = sL, t = sT;                    // t in [1, hist2[L]]
  const uint32_t binCnt = min(ct[1], (uint32_t)BINCAP);
  for (uint32_t i = threadIdx.x; i < binCnt; i += 1024) {
    unsigned long long key = binlist[(size_t)b * BINCAP + i];
    uint32_t low = ((uint32_t)(key >> 32)) & 0xFFFFu;
    if (low > L) {
      uint32_t pos = atomicAdd(&ct[0], 1u);
      cand[(size_t)b * KSEL + pos] = key;
    } else if (low == L) {
      uint32_t e = atomicAdd(&ct[2], 1u);
      if (e < (uint32_t)EQCAP) eqbuf[(size_t)b * EQCAP + e] = (uint32_t)key;  // ~idx
    }
  }
  __syncthreads();
  if (threadIdx.x == 0) sEq = atomicAdd(&ct[2], 0u);   // L2-fresh read
  __syncthreads();
  const uint32_t eqCnt = min(sEq, (uint32_t)EQCAP);
  for (uint32_t i = threadIdx.x; i < (uint32_t)EQCAP; i += 1024)
    eqs[i] = (i < eqCnt) ? eqbuf[(size_t)b * EQCAP + i] : 0u;  // pad 0 sinks (values ~0xFFE*)
  __syncthreads();
  // sort eqs descending: e = ~idx descending  <=>  idx ascending
  for (int kk = 2; kk <= EQCAP; kk <<= 1) {
    for (int j = kk >> 1; j > 0; j >>= 1) {
      for (int i = threadIdx.x; i < EQCAP; i += 1024) {
        int l = i ^ j;
        if (l > i) {
          uint32_t a = eqs[i], cc = eqs[l];
          bool descRegion = ((i & kk) == 0);
          if (descRegion ? (a < cc) : (a > cc)) { eqs[i] = cc; eqs[l] = a; }
        }
      }
      __syncthreads();
    }
  }
  const unsigned long long hi = ((unsigned long long)((P16 << 16) | L)) << 32;
  for (uint32_t r = threadIdx.x; r < t; r += 1024)
    cand[(size_t)b * KSEL + ((uint32_t)KSEL - t) + r] = hi | (unsigned long long)eqs[r];
}

__global__ __launch_bounds__(1024) void k_sortout(const unsigned long long* __restrict__ cand,
                                                  const float* __restrict__ mins,
                                                  const float* __restrict__ ranges,
                                                  const float* __restrict__ jitter,
                                                  float* __restrict__ out) {
  const int b = blockIdx.x;
  __shared__ unsigned long long sk[KSEL];          // 128 KiB
  for (int i = threadIdx.x; i < KSEL; i += 1024) sk[i] = cand[(size_t)b * KSEL + i];
  __syncthreads();
  for (int kk = 2; kk <= KSEL; kk <<= 1) {
    for (int j = kk >> 1; j > 0; j >>= 1) {
      for (int i = threadIdx.x; i < KSEL; i += 1024) {
        int l = i ^ j;
        if (l > i) {
          unsigned long long a = sk[i], c = sk[l];
          bool descRegion = ((i & kk) == 0);       // overall descending
          if (descRegion ? (a < c) : (a > c)) { sk[i] = c; sk[l] = a; }
        }
      }
      __syncthreads();
    }
  }
  const float mn0 = mins[b * 3 + 0], mn1 = mins[b * 3 + 1], mn2 = mins[b * 3 + 2];
  const float rg0 = ranges[b * 3 + 0], rg1 = ranges[b * 3 + 1], rg2 = ranges[b * 3 + 2];
  const float inv = 1.0f / 128.0f;
  for (int r = threadIdx.x; r < KSEL; r += 1024) {
    unsigned long long key = sk[r];
    uint32_t idx = 0xFFFFFFFFu - (uint32_t)key;
    float iz = (float)(idx >> 14);
    float iy = (float)((idx >> 7) & 127u);
    float ix = (float)(idx & 127u);
    const float* jt = jitter + ((size_t)b * KSEL + r) * 3;
    float* o = out + ((size_t)b * KSEL + r) * 3;
    o[0] = (iz + jt[0]) * inv * rg0 + mn0;
    o[1] = (iy + jt[1]) * inv * rg1 + mn1;
    o[2] = (ix + jt[2]) * inv * rg2 + mn2;
  }
}

extern "C" void kernel_launch(void* const* d_in, const int* in_sizes, int n_in,
                              void* d_out, int out_size, void* d_ws, size_t ws_size,
                              hipStream_t stream) {
  const float* vox    = (const float*)d_in[0];
  const float* mins   = (const float*)d_in[1];
  const float* ranges = (const float*)d_in[2];
  const float* jitter = (const float*)d_in[3];
  float* out = (float*)d_out;

  char* ws = (char*)d_ws;
  uint32_t* hist1 = (uint32_t*)(ws + 0);
  uint32_t* hist2 = (uint32_t*)(ws + 4194304);
  uint32_t* ctrl  = (uint32_t*)(ws + 8388608);             // 16*16 u32 = 1 KiB
  unsigned long long* cand    = (unsigned long long*)(ws + 8389632);   // 2 MiB
  unsigned long long* binlist = (unsigned long long*)(ws + 10486784);  // 2 MiB
  uint32_t* eqbuf = (uint32_t*)(ws + 12583936);            // 512 KiB
  if (ws_size < 13108224) return;

  hipMemsetAsync(ws, 0, 8389632, stream);                  // hist1+hist2+ctrl

  k_hist   <<<dim3(64, BATCH), 256, 0, stream>>>(vox, hist1);
  k_scan1  <<<BATCH, 1024, 0, stream>>>(hist1, ctrl);
  k_gather <<<dim3(64, BATCH), 256, 0, stream>>>(vox, ctrl, cand, binlist, hist2);
  k_finalize<<<BATCH, 1024, 0, stream>>>(hist2, ctrl, cand, binlist, eqbuf);
  k_sortout<<<BATCH, 1024, 0, stream>>>(cand, mins, ranges, jitter, out);
}

// Round 2
// 673.726 us; speedup vs baseline: 1.4740x; 1.4740x over previous
//
#include <hip/hip_runtime.h>
#include <stdint.h>

#define BATCH 16
#define NVOX (128*128*128)      // 2,097,152 per batch
#define KSEL 16384
#define HBINS 65536
#define BINCAP 16384
#define EQCAP 8192

// ctrl per batch: 16 u32: [0]=candCnt [1]=binCnt [2]=unused [3]=P16 [4]=Cgt16

__global__ __launch_bounds__(256) void k_hist(const float* __restrict__ vox,
                                              uint32_t* __restrict__ hist1) {
  const int b = blockIdx.y;
  __shared__ uint32_t lh[768];              // bins 0x3D00..0x3FFF (v >= 2^-5)
  for (int i = threadIdx.x; i < 768; i += 256) lh[i] = 0;
  __syncthreads();
  const float4* v4 = (const float4*)(vox + (size_t)b * NVOX);
  uint32_t* h = hist1 + (size_t)b * HBINS;
  const int n4 = NVOX / 4;
  for (int i = blockIdx.x * 256 + threadIdx.x; i < n4; i += gridDim.x * 256) {
    float4 v = v4[i];
    float f[4] = {v.x, v.y, v.z, v.w};
#pragma unroll
    for (int c = 0; c < 4; ++c) {
      if (f[c] > 0.0f) {
        uint32_t p16 = __float_as_uint(f[c]) >> 16;
        uint32_t w = p16 - 0x3D00u;
        if (w < 768u) atomicAdd(&lh[w], 1u);
        else          atomicAdd(&h[p16], 1u);
      }
    }
  }
  __syncthreads();
  for (int i = threadIdx.x; i < 768; i += 256)
    if (lh[i]) atomicAdd(&h[0x3D00u + i], lh[i]);
}

// Parallel threshold-bin search: 1024 threads, each sums a 64-bin chunk,
// block-wide suffix scan, unique cut thread refines within its chunk by wave scan.
__device__ __forceinline__ void find_cut(const uint32_t* __restrict__ h,
                                         uint32_t target,
                                         uint32_t* outBin, uint32_t* outAbove) {
  const int tid = threadIdx.x;
  __shared__ uint32_t buf[1024];
  __shared__ uint32_t sChunk, sRun;
  uint32_t s = 0;
  const uint4* h4 = (const uint4*)(h + tid * 64);
#pragma unroll
  for (int i = 0; i < 16; ++i) { uint4 q = h4[i]; s += q.x + q.y + q.z + q.w; }
  const uint32_t mySum = s;
  buf[tid] = s;
  __syncthreads();
  for (int off = 1; off < 1024; off <<= 1) {
    uint32_t v = (tid + off < 1024) ? buf[tid + off] : 0u;
    __syncthreads();
    buf[tid] += v;
    __syncthreads();
  }
  const uint32_t sufIncl = buf[tid];
  const uint32_t sufExcl = sufIncl - mySum;
  if (sufIncl >= target && sufExcl < target) { sChunk = (uint32_t)tid; sRun = sufExcl; }
  __syncthreads();
  const uint32_t c = sChunk, run = sRun;
  if (tid < 64) {
    const uint32_t hv = h[c * 64 + tid];
    uint32_t ss = hv;
    for (int off = 1; off < 64; off <<= 1) {
      uint32_t up = __shfl_down(ss, off);
      if (tid + off < 64) ss += up;
    }
    const uint32_t se = ss - hv;   // count in bins strictly above this bin (within chunk)
    if (run + ss >= target && run + se < target) {
      *outBin = c * 64 + (uint32_t)tid;
      *outAbove = run + se;
    }
  }
}

__global__ __launch_bounds__(1024) void k_scan1(const uint32_t* __restrict__ hist1,
                                                uint32_t* __restrict__ ctrl) {
  const int b = blockIdx.x;
  find_cut(hist1 + (size_t)b * HBINS, (uint32_t)KSEL,
           &ctrl[b * 16 + 3], &ctrl[b * 16 + 4]);
}

__global__ __launch_bounds__(256) void k_gather(const float* __restrict__ vox,
                                                uint32_t* __restrict__ ctrl,
                                                unsigned long long* __restrict__ cand,
                                                unsigned long long* __restrict__ binlist,
                                                uint32_t* __restrict__ hist2) {
  const int b = blockIdx.y;
  const uint32_t P16 = ctrl[b * 16 + 3];
  const float4* v4 = (const float4*)(vox + (size_t)b * NVOX);
  uint32_t* h2 = hist2 + (size_t)b * HBINS;
  const int n4 = NVOX / 4;
  const uint32_t lane = threadIdx.x & 63u;
  const unsigned long long lmask = (1ull << lane) - 1ull;
  for (int i = blockIdx.x * 256 + threadIdx.x; i < n4; i += gridDim.x * 256) {
    float4 v = v4[i];
    float f[4] = {v.x, v.y, v.z, v.w};
#pragma unroll
    for (int c = 0; c < 4; ++c) {
      const uint32_t bits = __float_as_uint(f[c]);
      const bool act = f[c] > 0.0f;
      const uint32_t p16 = bits >> 16;
      const bool isCand = act && (p16 > P16);
      const bool isBin  = act && (p16 == P16);
      const uint32_t idx = (uint32_t)(i * 4 + c);
      const unsigned long long key =
          ((unsigned long long)bits << 32) | (unsigned long long)(0xFFFFFFFFu - idx);
      unsigned long long mC = __ballot(isCand);
      if (mC) {
        const int leader = __ffsll(mC) - 1;
        uint32_t base = 0;
        if ((int)lane == leader) base = atomicAdd(&ctrl[b * 16 + 0], (uint32_t)__popcll(mC));
        base = __shfl(base, leader);
        if (isCand) cand[(size_t)b * KSEL + base + (uint32_t)__popcll(mC & lmask)] = key;
      }
      unsigned long long mB = __ballot(isBin);
      if (mB) {
        const int leader = __ffsll(mB) - 1;
        uint32_t base = 0;
        if ((int)lane == leader) base = atomicAdd(&ctrl[b * 16 + 1], (uint32_t)__popcll(mB));
        base = __shfl(base, leader);
        if (isBin) {
          const uint32_t pos = base + (uint32_t)__popcll(mB & lmask);
          if (pos < (uint32_t)BINCAP) binlist[(size_t)b * BINCAP + pos] = key;
          atomicAdd(&h2[bits & 0xFFFFu], 1u);   // no return value -> fire-and-forget
        }
      }
    }
  }
}

__global__ __launch_bounds__(1024) void k_finalize(const uint32_t* __restrict__ hist2,
                                                   uint32_t* __restrict__ ctrl,
                                                   unsigned long long* __restrict__ cand,
                                                   const unsigned long long* __restrict__ binlist) {
  const int b = blockIdx.x;
  const int tid = threadIdx.x;
  uint32_t* ct = ctrl + b * 16;
  const uint32_t Cgt16 = ct[4];
  const uint32_t P16 = ct[3];
  const uint32_t rem = (uint32_t)KSEL - Cgt16;     // >= 1
  __shared__ uint32_t sBin, sAbove;
  find_cut(hist2 + (size_t)b * HBINS, rem, &sBin, &sAbove);
  __syncthreads();
  const uint32_t L = sBin;
  const uint32_t t = rem - sAbove;                 // take t smallest-idx among equal-value set
  __shared__ uint32_t sCand, sEqCnt;
  __shared__ uint32_t eqs[EQCAP];
  if (tid == 0) { sCand = ct[0]; sEqCnt = 0; }
  __syncthreads();
  const uint32_t binCnt = min(ct[1], (uint32_t)BINCAP);
  for (uint32_t base = 0; base < binCnt; base += 1024) {
    const uint32_t i = base + (uint32_t)tid;
    if (i < binCnt) {
      const unsigned long long key = binlist[(size_t)b * BINCAP + i];
      const uint32_t low = ((uint32_t)(key >> 32)) & 0xFFFFu;
      if (low > L) {
        const uint32_t pos = atomicAdd(&sCand, 1u);
        cand[(size_t)b * KSEL + pos] = key;
      } else if (low == L) {
        const uint32_t e = atomicAdd(&sEqCnt, 1u);
        if (e < (uint32_t)EQCAP) eqs[e] = (uint32_t)key;     // ~idx
      }
    }
  }
  __syncthreads();
  const uint32_t eqCnt = min(sEqCnt, (uint32_t)EQCAP);
  uint32_t p2 = 1;
  while (p2 < eqCnt) p2 <<= 1;                     // typically tiny (ties are rare)
  for (uint32_t i = eqCnt + (uint32_t)tid; i < p2; i += 1024) eqs[i] = 0u;  // pad sinks
  __syncthreads();
  // sort eqs[0..p2) descending: ~idx descending == idx ascending
  for (uint32_t kk = 2; kk <= p2; kk <<= 1) {
    for (uint32_t j = kk >> 1; j > 0; j >>= 1) {
      for (uint32_t i = (uint32_t)tid; i < p2; i += 1024) {
        const uint32_t l = i ^ j;
        if (l > i) {
          const uint32_t a = eqs[i], cc = eqs[l];
          const bool desc = ((i & kk) == 0);
          if (desc ? (a < cc) : (a > cc)) { eqs[i] = cc; eqs[l] = a; }
        }
      }
      __syncthreads();
    }
  }
  const unsigned long long hi = ((unsigned long long)((P16 << 16) | L)) << 32;
  for (uint32_t r = (uint32_t)tid; r < t; r += 1024)
    cand[(size_t)b * KSEL + ((uint32_t)KSEL - t) + r] = hi | (unsigned long long)eqs[r];
}

#define SWZ(i) ((i) ^ (((i) >> 4) & 15))

__global__ __launch_bounds__(1024) void k_sortout(const unsigned long long* __restrict__ cand,
                                                  const float* __restrict__ mins,
                                                  const float* __restrict__ ranges,
                                                  const float* __restrict__ jitter,
                                                  float* __restrict__ out) {
  const int b = blockIdx.x;
  const int tid = threadIdx.x;
  __shared__ unsigned long long sk[KSEL];          // 128 KiB
  for (int i = tid; i < KSEL; i += 1024) sk[SWZ(i)] = cand[(size_t)b * KSEL + i];
  __syncthreads();
  unsigned long long v[16];
  const int base = tid * 16;
  // ---- register session: kk = 2..16 entirely in-thread ----
#pragma unroll
  for (int e = 0; e < 16; ++e) v[e] = sk[SWZ(base + e)];
#pragma unroll
  for (int kk = 2; kk <= 16; kk <<= 1) {
#pragma unroll
    for (int j = 8; j > 0; j >>= 1) {
      if (j >= kk) continue;
#pragma unroll
      for (int e = 0; e < 16; ++e) {
        const int l = e ^ j;
        if (l > e) {
          const bool desc = (((base + e) & kk) == 0);
          const unsigned long long a = v[e], c2 = v[l];
          if (desc ? (a < c2) : (a > c2)) { v[e] = c2; v[l] = a; }
        }
      }
    }
  }
#pragma unroll
  for (int e = 0; e < 16; ++e) sk[SWZ(base + e)] = v[e];
  __syncthreads();
  // ---- kk = 32..16384: LDS steps for j>=16, register session for j<=8 ----
  for (int kk = 32; kk <= KSEL; kk <<= 1) {
    for (int j = kk >> 1; j >= 16; j >>= 1) {
      const int jm1 = j - 1;
      for (int s = tid; s < KSEL / 2; s += 1024) {
        const int i = ((s & ~jm1) << 1) | (s & jm1);
        const int l = i | j;
        const bool desc = ((i & kk) == 0);
        const unsigned long long a = sk[SWZ(i)], c2 = sk[SWZ(l)];
        if (desc ? (a < c2) : (a > c2)) { sk[SWZ(i)] = c2; sk[SWZ(l)] = a; }
      }
      __syncthreads();
    }
    const bool desc = ((base & kk) == 0);
#pragma unroll
    for (int e = 0; e < 16; ++e) v[e] = sk[SWZ(base + e)];
#pragma unroll
    for (int j = 8; j > 0; j >>= 1) {
#pragma unroll
      for (int e = 0; e < 16; ++e) {
        const int l = e ^ j;
        if (l > e) {
          const unsigned long long a = v[e], c2 = v[l];
          if (desc ? (a < c2) : (a > c2)) { v[e] = c2; v[l] = a; }
        }
      }
    }
#pragma unroll
    for (int e = 0; e < 16; ++e) sk[SWZ(base + e)] = v[e];
    __syncthreads();
  }
  const float mn0 = mins[b * 3 + 0], mn1 = mins[b * 3 + 1], mn2 = mins[b * 3 + 2];
  const float rg0 = ranges[b * 3 + 0], rg1 = ranges[b * 3 + 1], rg2 = ranges[b * 3 + 2];
  const float inv = 1.0f / 128.0f;
  for (int r = tid; r < KSEL; r += 1024) {
    const unsigned long long key = sk[SWZ(r)];
    const uint32_t idx = 0xFFFFFFFFu - (uint32_t)key;
    const float iz = (float)(idx >> 14);
    const float iy = (float)((idx >> 7) & 127u);
    const float ix = (float)(idx & 127u);
    const float* jt = jitter + ((size_t)b * KSEL + r) * 3;
    float* o = out + ((size_t)b * KSEL + r) * 3;
    o[0] = (iz + jt[0]) * inv * rg0 + mn0;
    o[1] = (iy + jt[1]) * inv * rg1 + mn1;
    o[2] = (ix + jt[2]) * inv * rg2 + mn2;
  }
}

extern "C" void kernel_launch(void* const* d_in, const int* in_sizes, int n_in,
                              void* d_out, int out_size, void* d_ws, size_t ws_size,
                              hipStream_t stream) {
  const float* vox    = (const float*)d_in[0];
  const float* mins   = (const float*)d_in[1];
  const float* ranges = (const float*)d_in[2];
  const float* jitter = (const float*)d_in[3];
  float* out = (float*)d_out;

  char* ws = (char*)d_ws;
  uint32_t* hist1 = (uint32_t*)(ws + 0);                               // 4 MiB
  uint32_t* hist2 = (uint32_t*)(ws + 4194304);                         // 4 MiB
  uint32_t* ctrl  = (uint32_t*)(ws + 8388608);                         // 1 KiB
  unsigned long long* cand    = (unsigned long long*)(ws + 8389632);   // 2 MiB
  unsigned long long* binlist = (unsigned long long*)(ws + 10486784);  // 2 MiB
  if (ws_size < 12583936) return;

  hipMemsetAsync(ws, 0, 8389632, stream);                  // hist1+hist2+ctrl

  k_hist    <<<dim3(128, BATCH), 256, 0, stream>>>(vox, hist1);
  k_scan1   <<<BATCH, 1024, 0, stream>>>(hist1, ctrl);
  k_gather  <<<dim3(128, BATCH), 256, 0, stream>>>(vox, ctrl, cand, binlist, hist2);
  k_finalize<<<BATCH, 1024, 0, stream>>>(hist2, ctrl, cand, binlist);
  k_sortout <<<BATCH, 1024, 0, stream>>>(cand, mins, ranges, jitter, out);
}